// Round 6
// baseline (293.788 us; speedup 1.0000x reference)
//
#include <hip/hip_runtime.h>
#include <hip/hip_bf16.h>

// ---------------------------------------------------------------------------
// RPN_Modulator fused pipeline (3 kernels):
//   k_q   : qpart[s,k,bi,c] = partial_c' modulator[bi,c'] * pm_w[k,c,c']   (4-way K-split)
//   k_w2  : w2[k,bi,o,c] = bf16(po_w[k,o,c] * (sum_s qpart + pm_b[k,c]))   (row-major)
//   k_gemm: out[k,bi,o,n] = sum_c w2[o,c]*bf16(feats[k][b,c,n]) + po_b[k,o]
//
// Round-5: REVERT grid-stride (229us: loop-carried state cost ~20%/job; the
// generation-quantization model was wrong). Base = verified round-3 k_gemm
// (193us, one job per block, dim3(268,4)). Two independent minimal changes:
//  * k_gemm: nontemporal -> PLAIN stores. NT acks come from HBM fabric ->
//    vmcnt queue saturates at 64 stores/instance/wave and in-order vmcnt
//    couples next instance's a-loads to store drain. Plain stores ack at L2;
//    the harness fill kernels prove plain streaming stores of this exact
//    output buffer run at 6.5-6.8 TB/s.
//  * k_q: kill the 64-value x 6-step shfl butterfly (384 LDS-pipe ops/wave,
//    ~18us chip-wide). Lane=(bi,sub): each lane accumulates only its own bi
//    over chunks sg+16i (sg = wave*4+sub; 784 = 16*49, no tail). Reduction =
//    2 shfl steps over the 4-lane sub-group + 1KB LDS cross-wave combine.
// ---------------------------------------------------------------------------

typedef __bf16 bf16x8 __attribute__((ext_vector_type(8)));
typedef float  f32x4  __attribute__((ext_vector_type(4)));
typedef float  f32x16 __attribute__((ext_vector_type(16)));
typedef unsigned short u16;

__device__ __forceinline__ unsigned pack2(float lo, float hi) {
    __hip_bfloat162 h = __float22bfloat162_rn(make_float2(lo, hi));
    union { __hip_bfloat162 h; unsigned u; } cv; cv.h = h; return cv.u;
}

// tiles-of-128 per level: {200,50,13,4,1}, total 268
__device__ __forceinline__ void decode_tile(int x, int& k, int& nt, int& N, size_t& oo) {
    if (x < 200)      { k = 0; nt = x;       N = 25600; oo = 0; }
    else if (x < 250) { k = 1; nt = x - 200; N = 6400;  oo = 104857600; }
    else if (x < 263) { k = 2; nt = x - 250; N = 1600;  oo = 131072000; }
    else if (x < 267) { k = 3; nt = x - 263; N = 400;   oo = 137625600; }
    else              { k = 4; nt = x - 267; N = 100;   oo = 139264000; }
}

// ---------------- Kernel 1: q partials, 4-way split over K ----------------
// lane = (bi = lane>>2, sub = lane&3); subgroup sg = w*4+sub owns chunks
// sg + 16*i, i in [0,49). Each lane accumulates 4 o-values for its own bi.
__global__ __launch_bounds__(256) void k_q(
    const float* __restrict__ modulator,  // [16][12544]
    const float* __restrict__ pm_w,       // [5][256][12544]
    float* __restrict__ qpart)            // [4][5][16][256]
{
    const int o4 = blockIdx.x;            // o = o4 + {0,64,128,192}
    const int k  = blockIdx.y;
    const int s  = blockIdx.z;            // K quarter: chunks s*784 .. s*784+783
    const int t  = threadIdx.x;
    const int w  = t >> 6, lane = t & 63;
    const int bi = lane >> 2, sub = lane & 3;
    const int sg = w * 4 + sub;           // 0..15

    const float4* mod4 = (const float4*)modulator + (size_t)bi * 3136 + s * 784 + sg;
    const float4* wp0 = (const float4*)(pm_w + ((size_t)k * 256 + o4      ) * 12544) + s * 784 + sg;
    const float4* wp1 = (const float4*)(pm_w + ((size_t)k * 256 + o4 +  64) * 12544) + s * 784 + sg;
    const float4* wp2 = (const float4*)(pm_w + ((size_t)k * 256 + o4 + 128) * 12544) + s * 784 + sg;
    const float4* wp3 = (const float4*)(pm_w + ((size_t)k * 256 + o4 + 192) * 12544) + s * 784 + sg;

    float a0 = 0.f, a1 = 0.f, a2 = 0.f, a3 = 0.f;
#pragma unroll 7
    for (int i = 0; i < 49; ++i) {
        float4 m = mod4[i * 16];
        float4 x0 = wp0[i * 16], x1 = wp1[i * 16], x2 = wp2[i * 16], x3 = wp3[i * 16];
        a0 += x0.x * m.x + x0.y * m.y + x0.z * m.z + x0.w * m.w;
        a1 += x1.x * m.x + x1.y * m.y + x1.z * m.z + x1.w * m.w;
        a2 += x2.x * m.x + x2.y * m.y + x2.z * m.z + x2.w * m.w;
        a3 += x3.x * m.x + x3.y * m.y + x3.z * m.z + x3.w * m.w;
    }
    // reduce over sub within the 4-lane group (valid at sub==0)
    a0 += __shfl_down(a0, 1); a1 += __shfl_down(a1, 1);
    a2 += __shfl_down(a2, 1); a3 += __shfl_down(a3, 1);
    a0 += __shfl_down(a0, 2); a1 += __shfl_down(a1, 2);
    a2 += __shfl_down(a2, 2); a3 += __shfl_down(a3, 2);

    __shared__ float red[4][64];
    if (sub == 0) {
        red[w][bi * 4 + 0] = a0;
        red[w][bi * 4 + 1] = a1;
        red[w][bi * 4 + 2] = a2;
        red[w][bi * 4 + 3] = a3;
    }
    __syncthreads();
    if (t < 64) {
        float v = red[0][t] + red[1][t] + red[2][t] + red[3][t];
        int bii = t >> 2;
        int o   = o4 + (t & 3) * 64;
        qpart[(((size_t)s * 5 + k) * 16 + bii) * 256 + o] = v;
    }
}

// ---------------- Kernel 2: W2 = bf16(po_w * (sum qpart + pm_b)), 4c/thread
__global__ __launch_bounds__(256) void k_w2(
    const float* __restrict__ po_w,       // [5][256][256]
    const float* __restrict__ pm_b,       // [5][256]
    const float* __restrict__ qpart,      // [4][5][16][256]
    u16* __restrict__ w2)                 // [5][16][256][256] bf16
{
    int idx4 = blockIdx.x * 256 + threadIdx.x;   // 5*2^18 threads, 4 c each
    int c4 = idx4 & 63;
    int o  = (idx4 >> 6) & 255;
    int bi = (idx4 >> 14) & 15;
    int k  = idx4 >> 18;
    size_t qi = ((size_t)(k * 16 + bi)) * 256 + c4 * 4;
    f32x4 q0 = *(const f32x4*)(qpart + qi);
    f32x4 q1 = *(const f32x4*)(qpart + qi + 20480);
    f32x4 q2 = *(const f32x4*)(qpart + qi + 40960);
    f32x4 q3 = *(const f32x4*)(qpart + qi + 61440);
    f32x4 pb = *(const f32x4*)(pm_b + k * 256 + c4 * 4);
    f32x4 q  = q0 + q1 + q2 + q3 + pb;
    f32x4 w  = *(const f32x4*)(po_w + ((size_t)(k * 256 + o)) * 256 + c4 * 4);
    uint2 r;
    r.x = pack2(w[0] * q[0], w[1] * q[1]);
    r.y = pack2(w[2] * q[2], w[3] * q[3]);
    *(uint2*)(w2 + (size_t)idx4 * 4) = r;
}

// ---------------- Kernel 3: fused transpose + GEMM over all levels ---------
// block: 512 threads = 8 waves; 128 out-cols x full M=256 x 4 instances;
// each wave owns 32 o-rows via ONE 32-row m-tile, 4 n-tiles of 32 (32x32x16
// MFMA, acc 4 x f32x16). LDS: feats [128n][256c] bf16, h-swizzled. A direct
// from L2-resident w2. Every store instr = two full 128B lines. PLAIN stores
// (ack at L2, no vmcnt backpressure).
__global__ __launch_bounds__(512, 4) void k_gemm(
    const float* __restrict__ f0, const float* __restrict__ f1,
    const float* __restrict__ f2, const float* __restrict__ f3,
    const float* __restrict__ f4,
    const u16* __restrict__ w2,      // [k][bi][o][c] bf16 row-major
    const float* __restrict__ po_b,  // [5][256]
    float* __restrict__ out)         // [k][bi][o][n] fp32
{
    __shared__ __align__(16) u16 ldsB[128 * 256];   // 64 KB
    int k, nt, N; size_t oo;
    decode_tile(blockIdx.x, k, nt, N, oo);
    const float* fsrc = (k == 0) ? f0 : (k == 1) ? f1 : (k == 2) ? f2 : (k == 3) ? f3 : f4;
    const int b = blockIdx.y;
    const int t = threadIdx.x;
    const int n0 = nt * 128;

    // ---- stage: fp32 [c][n] -> bf16 LDS [n][c], h-swizzled b64 writes ----
    // thread: 4x4 register transpose; writes c-quad (8B) per n.
    {
        const int ng = t & 31, grp = t >> 5;    // ng: float4 along n; grp 0..15
        const bool inb = (n0 + ng * 4) < N;     // N%4==0 -> whole float4 in/out
        const float* s = fsrc + (size_t)b * 256 * N + n0 + ng * 4;
#pragma unroll
        for (int j = 0; j < 4; ++j) {
            int q = j * 16 + grp;               // c-quad: c = 4q..4q+3
            f32x4 v0 = {0.f,0.f,0.f,0.f}, v1 = {0.f,0.f,0.f,0.f};
            f32x4 v2 = {0.f,0.f,0.f,0.f}, v3 = {0.f,0.f,0.f,0.f};
            if (inb) {
                v0 = *(const f32x4*)(s + (size_t)(4 * q + 0) * N);
                v1 = *(const f32x4*)(s + (size_t)(4 * q + 1) * N);
                v2 = *(const f32x4*)(s + (size_t)(4 * q + 2) * N);
                v3 = *(const f32x4*)(s + (size_t)(4 * q + 3) * N);
            }
#pragma unroll
            for (int e = 0; e < 4; ++e) {
                int n = ng * 4 + e;
                unsigned h = ((unsigned)n & 7u) ^ (((unsigned)n >> 2) & 7u);
                unsigned off = ((unsigned)n << 9) + ((unsigned)q << 3);
                off ^= (h << 4);
                uint2 wv; wv.x = pack2(v0[e], v1[e]); wv.y = pack2(v2[e], v3[e]);
                *(uint2*)((char*)ldsB + off) = wv;
            }
        }
    }
    __syncthreads();

    const int lane = t & 63, w = t >> 6;        // 8 waves, 32 o-rows each
    const int l31 = lane & 31, lg5 = lane >> 5;
    const float* pb = po_b + k * 256;
    float* obase0 = out + oo;

    // bias: rows for acc reg q are w*32 + (q&3) + 8*(q>>2) + 4*lg5
    f32x4 bias4[4];
#pragma unroll
    for (int m = 0; m < 4; ++m)
        bias4[m] = *(const f32x4*)(pb + w * 32 + 8 * m + 4 * lg5);

    // B (feats) LDS addressing: row = ni*32 + l31; granule = (kk<<1)|lg5,
    // stored at granule ^ h(row). mrow = rowbase, mx = (lg5 ^ h)<<4;
    // addr = mrow + ((kk<<5) ^ mx)  (XOR safe: disjoint-carry by construction)
    unsigned mrow[4], mx[4];
#pragma unroll
    for (int ni = 0; ni < 4; ++ni) {
        int row = ni * 32 + l31;
        unsigned h = ((unsigned)row & 7u) ^ (((unsigned)row >> 2) & 7u);
        mrow[ni] = (unsigned)row << 9;
        mx[ni] = ((unsigned)lg5 ^ h) << 4;
    }

#pragma unroll 1
    for (int i = 0; i < 4; ++i) {
        // A (w2): row = w*32 + l31, k-bytes = kk*32 + lg5*16
        const u16* wsrc = w2 + ((size_t)(k * 16 + b * 4 + i) << 16)
                        + (size_t)(w * 32 + l31) * 256 + lg5 * 8;
        float* obase = obase0 + (size_t)(b * 4 + i) * 256 * N;

        f32x16 acc[4];
#pragma unroll
        for (int ni = 0; ni < 4; ++ni)
#pragma unroll
            for (int q = 0; q < 16; ++q)
                acc[ni][q] = bias4[q >> 2][q & 3];

#pragma unroll 2
        for (int kk = 0; kk < 16; ++kk) {       // K = 256 = 16 x 16
            bf16x8 a = *(const bf16x8*)(wsrc + kk * 16);
            bf16x8 bb[4];
            unsigned kb = (unsigned)kk << 5;
#pragma unroll
            for (int ni = 0; ni < 4; ++ni)
                bb[ni] = *(const bf16x8*)((const char*)ldsB + (mrow[ni] + (kb ^ mx[ni])));
#pragma unroll
            for (int ni = 0; ni < 4; ++ni)
                acc[ni] = __builtin_amdgcn_mfma_f32_32x32x16_bf16(a, bb[ni], acc[ni], 0, 0, 0);
        }

        // epilogue: D col = l31 (n), row = (q&3)+8*(q>>2)+4*lg5 (o).
        // Each store instr: 2 row-groups x 32 consecutive n = 2 full lines.
#pragma unroll
        for (int ni = 0; ni < 4; ++ni) {
            int ocol = n0 + ni * 32 + l31;
            if (ocol < N) {
                float* op = obase + ocol;
#pragma unroll
                for (int q = 0; q < 16; ++q) {
                    int orow = w * 32 + (q & 3) + 8 * (q >> 2) + 4 * lg5;
                    op[(size_t)orow * N] = acc[ni][q];
                }
            }
        }
    }
}

// ---------------------------------------------------------------------------
extern "C" void kernel_launch(void* const* d_in, const int* in_sizes, int n_in,
                              void* d_out, int out_size, void* d_ws, size_t ws_size,
                              hipStream_t stream) {
    const float* f0 = (const float*)d_in[0];
    const float* f1 = (const float*)d_in[1];
    const float* f2 = (const float*)d_in[2];
    const float* f3 = (const float*)d_in[3];
    const float* f4 = (const float*)d_in[4];
    const float* modulator = (const float*)d_in[5];
    const float* pm_w = (const float*)d_in[6];
    const float* pm_b = (const float*)d_in[7];
    const float* po_w = (const float*)d_in[8];
    const float* po_b = (const float*)d_in[9];
    float* out = (float*)d_out;

    // workspace: w2 bf16 (5,242,880 u16) | qpart (81,920 f32)  ~= 10.8 MB
    u16* w2 = (u16*)d_ws;
    float* qpart = (float*)(w2 + (size_t)5 * 16 * 256 * 256);

    k_q<<<dim3(64, 5, 4), 256, 0, stream>>>(modulator, pm_w, qpart);
    k_w2<<<5120, 256, 0, stream>>>(po_w, pm_b, qpart, w2);
    k_gemm<<<dim3(268, 4), 512, 0, stream>>>(f0, f1, f2, f3, f4, w2, po_b, out);
}

// Round 7
// 204.539 us; speedup vs baseline: 1.4363x; 1.4363x over previous
//
#include <hip/hip_runtime.h>
#include <hip/hip_bf16.h>

// ---------------------------------------------------------------------------
// RPN_Modulator fused pipeline (3 kernels):
//   k_q   : qpart[s,k,bi,c] = partial_c' modulator[bi,c'] * pm_w[k,c,c']   (4-way K-split)
//   k_w2  : w2[k,bi,o,c] = bf16(po_w[k,o,c] * (sum_s qpart + pm_b[k,c]))   (row-major)
//   k_gemm: out[k,bi,o,n] = sum_c w2[o,c]*bf16(feats[k][b,c,n]) + po_b[k,o]
//
// Round-6: RESTORE round-3 k_gemm exactly (193us config) -- NONTEMPORAL
// stores are load-bearing: plain stores write-allocate 559MB through the
// 4MiB/XCD L2 and evict the w2 working set, turning 546MB of A-load L2 hits
// into HBM misses (round-5: +100us). NT stores bypass/evict-first in L2 and
// protect it. Keep the round-5 k_q (4-lane-group reduction, 8 shfl instead
// of 384 cross-lane ops/wave) -- this round isolates its delta cleanly.
// ---------------------------------------------------------------------------

typedef __bf16 bf16x8 __attribute__((ext_vector_type(8)));
typedef float  f32x4  __attribute__((ext_vector_type(4)));
typedef float  f32x16 __attribute__((ext_vector_type(16)));
typedef unsigned short u16;

__device__ __forceinline__ unsigned pack2(float lo, float hi) {
    __hip_bfloat162 h = __float22bfloat162_rn(make_float2(lo, hi));
    union { __hip_bfloat162 h; unsigned u; } cv; cv.h = h; return cv.u;
}

// tiles-of-128 per level: {200,50,13,4,1}, total 268
__device__ __forceinline__ void decode_tile(int x, int& k, int& nt, int& N, size_t& oo) {
    if (x < 200)      { k = 0; nt = x;       N = 25600; oo = 0; }
    else if (x < 250) { k = 1; nt = x - 200; N = 6400;  oo = 104857600; }
    else if (x < 263) { k = 2; nt = x - 250; N = 1600;  oo = 131072000; }
    else if (x < 267) { k = 3; nt = x - 263; N = 400;   oo = 137625600; }
    else              { k = 4; nt = x - 267; N = 100;   oo = 139264000; }
}

// ---------------- Kernel 1: q partials, 4-way split over K ----------------
// lane = (bi = lane>>2, sub = lane&3); subgroup sg = w*4+sub owns chunks
// sg + 16*i, i in [0,49). Each lane accumulates 4 o-values for its own bi.
__global__ __launch_bounds__(256) void k_q(
    const float* __restrict__ modulator,  // [16][12544]
    const float* __restrict__ pm_w,       // [5][256][12544]
    float* __restrict__ qpart)            // [4][5][16][256]
{
    const int o4 = blockIdx.x;            // o = o4 + {0,64,128,192}
    const int k  = blockIdx.y;
    const int s  = blockIdx.z;            // K quarter: chunks s*784 .. s*784+783
    const int t  = threadIdx.x;
    const int w  = t >> 6, lane = t & 63;
    const int bi = lane >> 2, sub = lane & 3;
    const int sg = w * 4 + sub;           // 0..15

    const float4* mod4 = (const float4*)modulator + (size_t)bi * 3136 + s * 784 + sg;
    const float4* wp0 = (const float4*)(pm_w + ((size_t)k * 256 + o4      ) * 12544) + s * 784 + sg;
    const float4* wp1 = (const float4*)(pm_w + ((size_t)k * 256 + o4 +  64) * 12544) + s * 784 + sg;
    const float4* wp2 = (const float4*)(pm_w + ((size_t)k * 256 + o4 + 128) * 12544) + s * 784 + sg;
    const float4* wp3 = (const float4*)(pm_w + ((size_t)k * 256 + o4 + 192) * 12544) + s * 784 + sg;

    float a0 = 0.f, a1 = 0.f, a2 = 0.f, a3 = 0.f;
#pragma unroll 7
    for (int i = 0; i < 49; ++i) {
        float4 m = mod4[i * 16];
        float4 x0 = wp0[i * 16], x1 = wp1[i * 16], x2 = wp2[i * 16], x3 = wp3[i * 16];
        a0 += x0.x * m.x + x0.y * m.y + x0.z * m.z + x0.w * m.w;
        a1 += x1.x * m.x + x1.y * m.y + x1.z * m.z + x1.w * m.w;
        a2 += x2.x * m.x + x2.y * m.y + x2.z * m.z + x2.w * m.w;
        a3 += x3.x * m.x + x3.y * m.y + x3.z * m.z + x3.w * m.w;
    }
    // reduce over sub within the 4-lane group (valid at sub==0)
    a0 += __shfl_down(a0, 1); a1 += __shfl_down(a1, 1);
    a2 += __shfl_down(a2, 1); a3 += __shfl_down(a3, 1);
    a0 += __shfl_down(a0, 2); a1 += __shfl_down(a1, 2);
    a2 += __shfl_down(a2, 2); a3 += __shfl_down(a3, 2);

    __shared__ float red[4][64];
    if (sub == 0) {
        red[w][bi * 4 + 0] = a0;
        red[w][bi * 4 + 1] = a1;
        red[w][bi * 4 + 2] = a2;
        red[w][bi * 4 + 3] = a3;
    }
    __syncthreads();
    if (t < 64) {
        float v = red[0][t] + red[1][t] + red[2][t] + red[3][t];
        int bii = t >> 2;
        int o   = o4 + (t & 3) * 64;
        qpart[(((size_t)s * 5 + k) * 16 + bii) * 256 + o] = v;
    }
}

// ---------------- Kernel 2: W2 = bf16(po_w * (sum qpart + pm_b)), 4c/thread
__global__ __launch_bounds__(256) void k_w2(
    const float* __restrict__ po_w,       // [5][256][256]
    const float* __restrict__ pm_b,       // [5][256]
    const float* __restrict__ qpart,      // [4][5][16][256]
    u16* __restrict__ w2)                 // [5][16][256][256] bf16
{
    int idx4 = blockIdx.x * 256 + threadIdx.x;   // 5*2^18 threads, 4 c each
    int c4 = idx4 & 63;
    int o  = (idx4 >> 6) & 255;
    int bi = (idx4 >> 14) & 15;
    int k  = idx4 >> 18;
    size_t qi = ((size_t)(k * 16 + bi)) * 256 + c4 * 4;
    f32x4 q0 = *(const f32x4*)(qpart + qi);
    f32x4 q1 = *(const f32x4*)(qpart + qi + 20480);
    f32x4 q2 = *(const f32x4*)(qpart + qi + 40960);
    f32x4 q3 = *(const f32x4*)(qpart + qi + 61440);
    f32x4 pb = *(const f32x4*)(pm_b + k * 256 + c4 * 4);
    f32x4 q  = q0 + q1 + q2 + q3 + pb;
    f32x4 w  = *(const f32x4*)(po_w + ((size_t)(k * 256 + o)) * 256 + c4 * 4);
    uint2 r;
    r.x = pack2(w[0] * q[0], w[1] * q[1]);
    r.y = pack2(w[2] * q[2], w[3] * q[3]);
    *(uint2*)(w2 + (size_t)idx4 * 4) = r;
}

// ---------------- Kernel 3: fused transpose + GEMM over all levels ---------
// block: 512 threads = 8 waves; 128 out-cols x full M=256 x 4 instances;
// each wave owns 32 o-rows via ONE 32-row m-tile, 4 n-tiles of 32 (32x32x16
// MFMA, acc 4 x f32x16). LDS: feats [128n][256c] bf16, h-swizzled. A direct
// from L2-resident w2. Every NT store instr = two full 128B lines.
__global__ __launch_bounds__(512, 4) void k_gemm(
    const float* __restrict__ f0, const float* __restrict__ f1,
    const float* __restrict__ f2, const float* __restrict__ f3,
    const float* __restrict__ f4,
    const u16* __restrict__ w2,      // [k][bi][o][c] bf16 row-major
    const float* __restrict__ po_b,  // [5][256]
    float* __restrict__ out)         // [k][bi][o][n] fp32
{
    __shared__ __align__(16) u16 ldsB[128 * 256];   // 64 KB
    int k, nt, N; size_t oo;
    decode_tile(blockIdx.x, k, nt, N, oo);
    const float* fsrc = (k == 0) ? f0 : (k == 1) ? f1 : (k == 2) ? f2 : (k == 3) ? f3 : f4;
    const int b = blockIdx.y;
    const int t = threadIdx.x;
    const int n0 = nt * 128;

    // ---- stage: fp32 [c][n] -> bf16 LDS [n][c], h-swizzled b64 writes ----
    // thread: 4x4 register transpose; writes c-quad (8B) per n.
    {
        const int ng = t & 31, grp = t >> 5;    // ng: float4 along n; grp 0..15
        const bool inb = (n0 + ng * 4) < N;     // N%4==0 -> whole float4 in/out
        const float* s = fsrc + (size_t)b * 256 * N + n0 + ng * 4;
#pragma unroll
        for (int j = 0; j < 4; ++j) {
            int q = j * 16 + grp;               // c-quad: c = 4q..4q+3
            f32x4 v0 = {0.f,0.f,0.f,0.f}, v1 = {0.f,0.f,0.f,0.f};
            f32x4 v2 = {0.f,0.f,0.f,0.f}, v3 = {0.f,0.f,0.f,0.f};
            if (inb) {
                v0 = *(const f32x4*)(s + (size_t)(4 * q + 0) * N);
                v1 = *(const f32x4*)(s + (size_t)(4 * q + 1) * N);
                v2 = *(const f32x4*)(s + (size_t)(4 * q + 2) * N);
                v3 = *(const f32x4*)(s + (size_t)(4 * q + 3) * N);
            }
#pragma unroll
            for (int e = 0; e < 4; ++e) {
                int n = ng * 4 + e;
                unsigned h = ((unsigned)n & 7u) ^ (((unsigned)n >> 2) & 7u);
                unsigned off = ((unsigned)n << 9) + ((unsigned)q << 3);
                off ^= (h << 4);
                uint2 wv; wv.x = pack2(v0[e], v1[e]); wv.y = pack2(v2[e], v3[e]);
                *(uint2*)((char*)ldsB + off) = wv;
            }
        }
    }
    __syncthreads();

    const int lane = t & 63, w = t >> 6;        // 8 waves, 32 o-rows each
    const int l31 = lane & 31, lg5 = lane >> 5;
    const float* pb = po_b + k * 256;
    float* obase0 = out + oo;

    // bias: rows for acc reg q are w*32 + (q&3) + 8*(q>>2) + 4*lg5
    f32x4 bias4[4];
#pragma unroll
    for (int m = 0; m < 4; ++m)
        bias4[m] = *(const f32x4*)(pb + w * 32 + 8 * m + 4 * lg5);

    // B (feats) LDS addressing: row = ni*32 + l31; granule = (kk<<1)|lg5,
    // stored at granule ^ h(row). mrow = rowbase, mx = (lg5 ^ h)<<4;
    // addr = mrow + ((kk<<5) ^ mx)  (XOR safe: disjoint-carry by construction)
    unsigned mrow[4], mx[4];
#pragma unroll
    for (int ni = 0; ni < 4; ++ni) {
        int row = ni * 32 + l31;
        unsigned h = ((unsigned)row & 7u) ^ (((unsigned)row >> 2) & 7u);
        mrow[ni] = (unsigned)row << 9;
        mx[ni] = ((unsigned)lg5 ^ h) << 4;
    }

#pragma unroll 1
    for (int i = 0; i < 4; ++i) {
        // A (w2): row = w*32 + l31, k-bytes = kk*32 + lg5*16
        const u16* wsrc = w2 + ((size_t)(k * 16 + b * 4 + i) << 16)
                        + (size_t)(w * 32 + l31) * 256 + lg5 * 8;
        float* obase = obase0 + (size_t)(b * 4 + i) * 256 * N;

        f32x16 acc[4];
#pragma unroll
        for (int ni = 0; ni < 4; ++ni)
#pragma unroll
            for (int q = 0; q < 16; ++q)
                acc[ni][q] = bias4[q >> 2][q & 3];

#pragma unroll 2
        for (int kk = 0; kk < 16; ++kk) {       // K = 256 = 16 x 16
            bf16x8 a = *(const bf16x8*)(wsrc + kk * 16);
            bf16x8 bb[4];
            unsigned kb = (unsigned)kk << 5;
#pragma unroll
            for (int ni = 0; ni < 4; ++ni)
                bb[ni] = *(const bf16x8*)((const char*)ldsB + (mrow[ni] + (kb ^ mx[ni])));
#pragma unroll
            for (int ni = 0; ni < 4; ++ni)
                acc[ni] = __builtin_amdgcn_mfma_f32_32x32x16_bf16(a, bb[ni], acc[ni], 0, 0, 0);
        }

        // epilogue: D col = l31 (n), row = (q&3)+8*(q>>2)+4*lg5 (o).
        // Each store instr: 2 row-groups x 32 consecutive n = 2 full lines.
#pragma unroll
        for (int ni = 0; ni < 4; ++ni) {
            int ocol = n0 + ni * 32 + l31;
            if (ocol < N) {
                float* op = obase + ocol;
#pragma unroll
                for (int q = 0; q < 16; ++q) {
                    int orow = w * 32 + (q & 3) + 8 * (q >> 2) + 4 * lg5;
                    __builtin_nontemporal_store(acc[ni][q], op + (size_t)orow * N);
                }
            }
        }
    }
}

// ---------------------------------------------------------------------------
extern "C" void kernel_launch(void* const* d_in, const int* in_sizes, int n_in,
                              void* d_out, int out_size, void* d_ws, size_t ws_size,
                              hipStream_t stream) {
    const float* f0 = (const float*)d_in[0];
    const float* f1 = (const float*)d_in[1];
    const float* f2 = (const float*)d_in[2];
    const float* f3 = (const float*)d_in[3];
    const float* f4 = (const float*)d_in[4];
    const float* modulator = (const float*)d_in[5];
    const float* pm_w = (const float*)d_in[6];
    const float* pm_b = (const float*)d_in[7];
    const float* po_w = (const float*)d_in[8];
    const float* po_b = (const float*)d_in[9];
    float* out = (float*)d_out;

    // workspace: w2 bf16 (5,242,880 u16) | qpart (81,920 f32)  ~= 10.8 MB
    u16* w2 = (u16*)d_ws;
    float* qpart = (float*)(w2 + (size_t)5 * 16 * 256 * 256);

    k_q<<<dim3(64, 5, 4), 256, 0, stream>>>(modulator, pm_w, qpart);
    k_w2<<<5120, 256, 0, stream>>>(po_w, pm_b, qpart, w2);
    k_gemm<<<dim3(268, 4), 512, 0, stream>>>(f0, f1, f2, f3, f4, w2, po_b, out);
}

// Round 8
// 195.129 us; speedup vs baseline: 1.5056x; 1.0482x over previous
//
#include <hip/hip_runtime.h>
#include <hip/hip_bf16.h>

// ---------------------------------------------------------------------------
// RPN_Modulator fused pipeline (3 kernels):
//   k_q   : qpart[s,k,bi,c] = partial_c' modulator[bi,c'] * pm_w[k,c,c']   (4-way K-split)
//   k_w2  : w2[k,bi,o,c] = bf16(po_w[k,o,c] * (sum_s qpart + pm_b[k,c]))   (row-major)
//   k_gemm: out[k,bi,o,n] = sum_c w2[o,c]*bf16(feats[k][b,c,n]) + po_b[k,o]
//
// Round-7: (a) REVERT k_q to the round-3 coalesced version -- the 4-lane-
// group variant cost +11us (modulator reads scattered to 16 rows x 64B vs
// fully-coalesced 1KB bursts; the butterfly it removed was overlapped with
// loads anyway). (b) k_gemm: XCD-aware block swizzle. 1072 jobs = 8 x 134
// exactly -> bijective jsw = (flat%8)*134 + flat/8; each XCD gets one
// contiguous 134-job run = single b, stable ~512KB w2 slab set in its L2
// (was: consecutive same-slab blocks round-robined over 8 XCDs, 8x slab
// re-fetch + cross-b competition). NT stores stay (L2-protecting, round-6
// verified); 32x32x16 MFMA + conflict-free h-swizzle staging stay.
// ---------------------------------------------------------------------------

typedef __bf16 bf16x8 __attribute__((ext_vector_type(8)));
typedef float  f32x4  __attribute__((ext_vector_type(4)));
typedef float  f32x16 __attribute__((ext_vector_type(16)));
typedef unsigned short u16;

__device__ __forceinline__ unsigned pack2(float lo, float hi) {
    __hip_bfloat162 h = __float22bfloat162_rn(make_float2(lo, hi));
    union { __hip_bfloat162 h; unsigned u; } cv; cv.h = h; return cv.u;
}

// tiles-of-128 per level: {200,50,13,4,1}, total 268
__device__ __forceinline__ void decode_tile(int x, int& k, int& nt, int& N, size_t& oo) {
    if (x < 200)      { k = 0; nt = x;       N = 25600; oo = 0; }
    else if (x < 250) { k = 1; nt = x - 200; N = 6400;  oo = 104857600; }
    else if (x < 263) { k = 2; nt = x - 250; N = 1600;  oo = 131072000; }
    else if (x < 267) { k = 3; nt = x - 263; N = 400;   oo = 137625600; }
    else              { k = 4; nt = x - 267; N = 100;   oo = 139264000; }
}

// ---------------- Kernel 1: q partials, 4-way split over K ----------------
// (round-3 version: fully-coalesced loads, 64-lane butterfly reduce)
__global__ __launch_bounds__(256) void k_q(
    const float* __restrict__ modulator,  // [16][12544]
    const float* __restrict__ pm_w,       // [5][256][12544]
    float* __restrict__ qpart)            // [4][5][16][256]
{
    int o4 = blockIdx.x;                  // outputs o4 + {0,64,128,192}
    int k  = blockIdx.y;
    int s  = blockIdx.z;                  // K-split 0..3, 784 float4 each
    int t  = threadIdx.x;
    float acc[4][16];
#pragma unroll
    for (int j = 0; j < 4; ++j)
#pragma unroll
        for (int bi = 0; bi < 16; ++bi) acc[j][bi] = 0.f;
    const float4* mod4 = (const float4*)modulator;
    const float4* wp0 = (const float4*)(pm_w + ((size_t)k * 256 + o4      ) * 12544);
    const float4* wp1 = (const float4*)(pm_w + ((size_t)k * 256 + o4 +  64) * 12544);
    const float4* wp2 = (const float4*)(pm_w + ((size_t)k * 256 + o4 + 128) * 12544);
    const float4* wp3 = (const float4*)(pm_w + ((size_t)k * 256 + o4 + 192) * 12544);
    for (int it = 0; it < 4; ++it) {
        int jj = it * 256 + t;
        if (jj < 784) {
            int jx = s * 784 + jj;
            float4 wv0 = wp0[jx], wv1 = wp1[jx], wv2 = wp2[jx], wv3 = wp3[jx];
#pragma unroll
            for (int bi = 0; bi < 16; ++bi) {
                float4 m = mod4[bi * 3136 + jx];
                acc[0][bi] += wv0.x * m.x + wv0.y * m.y + wv0.z * m.z + wv0.w * m.w;
                acc[1][bi] += wv1.x * m.x + wv1.y * m.y + wv1.z * m.z + wv1.w * m.w;
                acc[2][bi] += wv2.x * m.x + wv2.y * m.y + wv2.z * m.z + wv2.w * m.w;
                acc[3][bi] += wv3.x * m.x + wv3.y * m.y + wv3.z * m.z + wv3.w * m.w;
            }
        }
    }
#pragma unroll
    for (int j = 0; j < 4; ++j)
#pragma unroll
        for (int bi = 0; bi < 16; ++bi)
#pragma unroll
            for (int off = 32; off > 0; off >>= 1)
                acc[j][bi] += __shfl_down(acc[j][bi], off);
    __shared__ float red[4][64];
    int w = t >> 6, lane = t & 63;
    if (lane == 0) {
#pragma unroll
        for (int j = 0; j < 4; ++j)
#pragma unroll
            for (int bi = 0; bi < 16; ++bi) red[w][j * 16 + bi] = acc[j][bi];
    }
    __syncthreads();
    if (t < 64) {
        float v = red[0][t] + red[1][t] + red[2][t] + red[3][t];
        int bi = t & 15;
        int o  = o4 + (t >> 4) * 64;
        qpart[(((size_t)s * 5 + k) * 16 + bi) * 256 + o] = v;
    }
}

// ---------------- Kernel 2: W2 = bf16(po_w * (sum qpart + pm_b)), 4c/thread
__global__ __launch_bounds__(256) void k_w2(
    const float* __restrict__ po_w,       // [5][256][256]
    const float* __restrict__ pm_b,       // [5][256]
    const float* __restrict__ qpart,      // [4][5][16][256]
    u16* __restrict__ w2)                 // [5][16][256][256] bf16
{
    int idx4 = blockIdx.x * 256 + threadIdx.x;   // 5*2^18 threads, 4 c each
    int c4 = idx4 & 63;
    int o  = (idx4 >> 6) & 255;
    int bi = (idx4 >> 14) & 15;
    int k  = idx4 >> 18;
    size_t qi = ((size_t)(k * 16 + bi)) * 256 + c4 * 4;
    f32x4 q0 = *(const f32x4*)(qpart + qi);
    f32x4 q1 = *(const f32x4*)(qpart + qi + 20480);
    f32x4 q2 = *(const f32x4*)(qpart + qi + 40960);
    f32x4 q3 = *(const f32x4*)(qpart + qi + 61440);
    f32x4 pb = *(const f32x4*)(pm_b + k * 256 + c4 * 4);
    f32x4 q  = q0 + q1 + q2 + q3 + pb;
    f32x4 w  = *(const f32x4*)(po_w + ((size_t)(k * 256 + o)) * 256 + c4 * 4);
    uint2 r;
    r.x = pack2(w[0] * q[0], w[1] * q[1]);
    r.y = pack2(w[2] * q[2], w[3] * q[3]);
    *(uint2*)(w2 + (size_t)idx4 * 4) = r;
}

// ---------------- Kernel 3: fused transpose + GEMM over all levels ---------
// 1072 blocks, XCD-swizzled job decode. block: 512 threads = 8 waves;
// 128 out-cols x full M=256 x 4 instances; each wave owns 32 o-rows
// (32x32x16 MFMA, acc 4 x f32x16). LDS: feats [128n][256c] bf16,
// h-swizzled. A direct from L2-resident w2. NT stores: 2 full 128B lines
// per instr, L2 protected.
__global__ __launch_bounds__(512, 4) void k_gemm(
    const float* __restrict__ f0, const float* __restrict__ f1,
    const float* __restrict__ f2, const float* __restrict__ f3,
    const float* __restrict__ f4,
    const u16* __restrict__ w2,      // [k][bi][o][c] bf16 row-major
    const float* __restrict__ po_b,  // [5][256]
    float* __restrict__ out)         // [k][bi][o][n] fp32
{
    __shared__ __align__(16) u16 ldsB[128 * 256];   // 64 KB
    // XCD swizzle: 1072 = 8*134 -> bijective; each XCD gets a contiguous
    // 134-job run (one b, stable w2 slab set in its private L2).
    const int flat = blockIdx.x;
    const int jsw = (flat & 7) * 134 + (flat >> 3);
    const int b = jsw / 268;
    const int tile = jsw - b * 268;
    int k, nt, N; size_t oo;
    decode_tile(tile, k, nt, N, oo);
    const float* fsrc = (k == 0) ? f0 : (k == 1) ? f1 : (k == 2) ? f2 : (k == 3) ? f3 : f4;
    const int t = threadIdx.x;
    const int n0 = nt * 128;

    // ---- stage: fp32 [c][n] -> bf16 LDS [n][c], h-swizzled b64 writes ----
    // thread: 4x4 register transpose; writes c-quad (8B) per n.
    {
        const int ng = t & 31, grp = t >> 5;    // ng: float4 along n; grp 0..15
        const bool inb = (n0 + ng * 4) < N;     // N%4==0 -> whole float4 in/out
        const float* s = fsrc + (size_t)b * 256 * N + n0 + ng * 4;
#pragma unroll
        for (int j = 0; j < 4; ++j) {
            int q = j * 16 + grp;               // c-quad: c = 4q..4q+3
            f32x4 v0 = {0.f,0.f,0.f,0.f}, v1 = {0.f,0.f,0.f,0.f};
            f32x4 v2 = {0.f,0.f,0.f,0.f}, v3 = {0.f,0.f,0.f,0.f};
            if (inb) {
                v0 = *(const f32x4*)(s + (size_t)(4 * q + 0) * N);
                v1 = *(const f32x4*)(s + (size_t)(4 * q + 1) * N);
                v2 = *(const f32x4*)(s + (size_t)(4 * q + 2) * N);
                v3 = *(const f32x4*)(s + (size_t)(4 * q + 3) * N);
            }
#pragma unroll
            for (int e = 0; e < 4; ++e) {
                int n = ng * 4 + e;
                unsigned h = ((unsigned)n & 7u) ^ (((unsigned)n >> 2) & 7u);
                unsigned off = ((unsigned)n << 9) + ((unsigned)q << 3);
                off ^= (h << 4);
                uint2 wv; wv.x = pack2(v0[e], v1[e]); wv.y = pack2(v2[e], v3[e]);
                *(uint2*)((char*)ldsB + off) = wv;
            }
        }
    }
    __syncthreads();

    const int lane = t & 63, w = t >> 6;        // 8 waves, 32 o-rows each
    const int l31 = lane & 31, lg5 = lane >> 5;
    const float* pb = po_b + k * 256;
    float* obase0 = out + oo;

    // bias: rows for acc reg q are w*32 + (q&3) + 8*(q>>2) + 4*lg5
    f32x4 bias4[4];
#pragma unroll
    for (int m = 0; m < 4; ++m)
        bias4[m] = *(const f32x4*)(pb + w * 32 + 8 * m + 4 * lg5);

    // B (feats) LDS addressing: row = ni*32 + l31; granule = (kk<<1)|lg5,
    // stored at granule ^ h(row). mrow = rowbase, mx = (lg5 ^ h)<<4;
    // addr = mrow + ((kk<<5) ^ mx)  (XOR safe: disjoint-carry by construction)
    unsigned mrow[4], mx[4];
#pragma unroll
    for (int ni = 0; ni < 4; ++ni) {
        int row = ni * 32 + l31;
        unsigned h = ((unsigned)row & 7u) ^ (((unsigned)row >> 2) & 7u);
        mrow[ni] = (unsigned)row << 9;
        mx[ni] = ((unsigned)lg5 ^ h) << 4;
    }

#pragma unroll 1
    for (int i = 0; i < 4; ++i) {
        // A (w2): row = w*32 + l31, k-bytes = kk*32 + lg5*16
        const u16* wsrc = w2 + ((size_t)(k * 16 + b * 4 + i) << 16)
                        + (size_t)(w * 32 + l31) * 256 + lg5 * 8;
        float* obase = obase0 + (size_t)(b * 4 + i) * 256 * N;

        f32x16 acc[4];
#pragma unroll
        for (int ni = 0; ni < 4; ++ni)
#pragma unroll
            for (int q = 0; q < 16; ++q)
                acc[ni][q] = bias4[q >> 2][q & 3];

#pragma unroll 2
        for (int kk = 0; kk < 16; ++kk) {       // K = 256 = 16 x 16
            bf16x8 a = *(const bf16x8*)(wsrc + kk * 16);
            bf16x8 bb[4];
            unsigned kb = (unsigned)kk << 5;
#pragma unroll
            for (int ni = 0; ni < 4; ++ni)
                bb[ni] = *(const bf16x8*)((const char*)ldsB + (mrow[ni] + (kb ^ mx[ni])));
#pragma unroll
            for (int ni = 0; ni < 4; ++ni)
                acc[ni] = __builtin_amdgcn_mfma_f32_32x32x16_bf16(a, bb[ni], acc[ni], 0, 0, 0);
        }

        // epilogue: D col = l31 (n), row = (q&3)+8*(q>>2)+4*lg5 (o).
        // Each store instr: 2 row-groups x 32 consecutive n = 2 full lines.
#pragma unroll
        for (int ni = 0; ni < 4; ++ni) {
            int ocol = n0 + ni * 32 + l31;
            if (ocol < N) {
                float* op = obase + ocol;
#pragma unroll
                for (int q = 0; q < 16; ++q) {
                    int orow = w * 32 + (q & 3) + 8 * (q >> 2) + 4 * lg5;
                    __builtin_nontemporal_store(acc[ni][q], op + (size_t)orow * N);
                }
            }
        }
    }
}

// ---------------------------------------------------------------------------
extern "C" void kernel_launch(void* const* d_in, const int* in_sizes, int n_in,
                              void* d_out, int out_size, void* d_ws, size_t ws_size,
                              hipStream_t stream) {
    const float* f0 = (const float*)d_in[0];
    const float* f1 = (const float*)d_in[1];
    const float* f2 = (const float*)d_in[2];
    const float* f3 = (const float*)d_in[3];
    const float* f4 = (const float*)d_in[4];
    const float* modulator = (const float*)d_in[5];
    const float* pm_w = (const float*)d_in[6];
    const float* pm_b = (const float*)d_in[7];
    const float* po_w = (const float*)d_in[8];
    const float* po_b = (const float*)d_in[9];
    float* out = (float*)d_out;

    // workspace: w2 bf16 (5,242,880 u16) | qpart (81,920 f32)  ~= 10.8 MB
    u16* w2 = (u16*)d_ws;
    float* qpart = (float*)(w2 + (size_t)5 * 16 * 256 * 256);

    k_q<<<dim3(64, 5, 4), 256, 0, stream>>>(modulator, pm_w, qpart);
    k_w2<<<5120, 256, 0, stream>>>(po_w, pm_b, qpart, w2);
    k_gemm<<<1072, 512, 0, stream>>>(f0, f1, f2, f3, f4, w2, po_b, out);
}